// Round 10
// baseline (632.207 us; speedup 1.0000x reference)
//
#include <hip/hip_runtime.h>

#define N_ENT   100000
#define N_REL   500
#define DD      50
#define LD      52      // fp32 stride for sequentially-read tables (EW1/Ed/e0): 208 B
#define LD2     64      // fp32 stride for RW (L2-resident gather): 256 B
#define LDH     64      // bf16 stride for EW3h: 64 shorts = 128 B = 1 cache line
#define N_EDGES 2000000
#define T_BITS  17
#define T_MASK  0x1FFFF
#define BBITS   9                    // 512 entities per coarse bucket
#define BMASK   511
#define NB      196                  // ceil(N_ENT / 512)
#define CHUNK   8192                 // edges per bucket_scatter block
#define MT6     64                   // rows per ent_pre_v6 block

__device__ inline unsigned int pack_bf2(float x, float y) {
    unsigned int xu = __float_as_uint(x);
    unsigned int yu = __float_as_uint(y);
    xu = (xu + 0x7FFFu + ((xu >> 16) & 1u)) >> 16;   // round-to-nearest-even
    yu = (yu + 0x7FFFu + ((yu >> 16) & 1u)) >> 16;
    return xu | (yu << 16);
}

// ---------------------------------------------------------------------------
// ent_pre_v6: register-blocked small GEMM (8 rows x 4 cols x NMAT per thread).
//   Ya[m][:]  = X@Wa   fp32 stride LD  ; shOut[m] = row.a
//   Ybh[m][:] = X@Wb   bf16 stride LDH ; stOut[m] = row.a (dot of bf16 vals)
//   Yc[m][:]  = X@Wc+bd fp32 stride LD   [NMAT==3 only]
// W staged in LDS at stride 52, zero-padded rows/cols 50,51 -> unguarded
// float4 k-loop (13 iters of 4). X staged at stride 52, pad cols zeroed.
// Block = 128 threads (104 compute: 8 row-groups x 13 col-quads), MT6=64 rows.
// ---------------------------------------------------------------------------
template<int NMAT>
__global__ __launch_bounds__(128) void ent_pre_v6(
    const float* __restrict__ X, int ldX, int Mrows,
    const float* __restrict__ Wa,
    const float* __restrict__ Wb,
    const float* __restrict__ Wc,
    const float* __restrict__ bd,
    const float* __restrict__ avec,
    float* __restrict__ Ya,
    unsigned short* __restrict__ Ybh,
    float* __restrict__ Yc,
    float* __restrict__ shOut,
    float* __restrict__ stOut)
{
    __shared__ __align__(16) float sW[NMAT][52 * 52];
    __shared__ __align__(16) float sXY[MT6 * 52];       // X, then fp32 Y staging
    __shared__ __align__(16) unsigned int sYh[MT6 * 32]; // bf16 Y staging
    __shared__ float sa[52];

    const int tid = threadIdx.x;
    const int m0 = blockIdx.x * MT6;
    const int nrow = min(MT6, Mrows - m0);

    if (tid < 52) sa[tid] = (tid < DD) ? avec[tid] : 0.f;

    // ---- stage W at stride 52, zero pads (rows/cols 50,51) ----
    for (int i = tid; i < 52 * 52; i += 128) {
        int k = i / 52, j = i - k * 52;
        bool in = (k < DD) && (j < DD);
        sW[0][i] = in ? Wa[k * DD + j] : 0.f;
        sW[1][i] = in ? Wb[k * DD + j] : 0.f;
        if (NMAT == 3) sW[2][i] = in ? Wc[k * DD + j] : 0.f;
    }

    // ---- stage X at stride 52 (+zero pad cols) ----
    if (ldX == 52) {
        const float4* xsrc = (const float4*)(X + (size_t)m0 * 52);
        for (int i = tid; i < nrow * 13; i += 128) ((float4*)sXY)[i] = xsrc[i];
        if (tid < MT6 * 2) sXY[(tid >> 1) * 52 + 50 + (tid & 1)] = 0.f;  // re-zero pads
    } else {
        for (int i = tid; i < nrow * DD; i += 128) {
            int row = i / DD, col = i - row * DD;
            sXY[row * 52 + col] = X[(size_t)(m0 + row) * ldX + col];
        }
        if (tid < MT6 * 2) sXY[(tid >> 1) * 52 + 50 + (tid & 1)] = 0.f;
    }
    __syncthreads();

    // ---- compute: 8x4 register tile per thread ----
    const bool active = (tid < 104);
    const int rg = tid / 13, cq = tid - rg * 13;
    const int r0 = rg * 8, j0 = cq * 4;

    float acc[NMAT][8][4];
    #pragma unroll
    for (int t = 0; t < NMAT; t++)
        #pragma unroll
        for (int i = 0; i < 8; i++)
            #pragma unroll
            for (int c = 0; c < 4; c++) acc[t][i][c] = 0.f;
    if (NMAT == 3 && active) {
        #pragma unroll
        for (int c = 0; c < 4; c++) {
            float b = (j0 + c < DD) ? bd[j0 + c] : 0.f;
            #pragma unroll
            for (int i = 0; i < 8; i++) acc[2][i][c] = b;
        }
    }

    if (active) {
        for (int k4 = 0; k4 < 52; k4 += 4) {
            float4 xv[8];
            #pragma unroll
            for (int i = 0; i < 8; i++)
                xv[i] = *(const float4*)&sXY[(r0 + i) * 52 + k4];
            #pragma unroll
            for (int kk = 0; kk < 4; kk++) {
                #pragma unroll
                for (int t = 0; t < NMAT; t++) {
                    float4 w = *(const float4*)&sW[t][(k4 + kk) * 52 + j0];
                    #pragma unroll
                    for (int i = 0; i < 8; i++) {
                        float x = (kk == 0) ? xv[i].x : (kk == 1) ? xv[i].y
                                : (kk == 2) ? xv[i].z : xv[i].w;
                        acc[t][i][0] += x * w.x;
                        acc[t][i][1] += x * w.y;
                        acc[t][i][2] += x * w.z;
                        acc[t][i][3] += x * w.w;
                    }
                }
            }
        }
    }

    __syncthreads();   // X dead

    // ---- stage acc[0] (fp32) and acc[1] (bf16) ----
    if (active) {
        #pragma unroll
        for (int i = 0; i < 8; i++) {
            int row = r0 + i;
            if (cq < 12) {
                *(float4*)&sXY[row * 52 + j0] =
                    make_float4(acc[0][i][0], acc[0][i][1], acc[0][i][2], acc[0][i][3]);
                sYh[row * 32 + cq * 2]     = pack_bf2(acc[1][i][0], acc[1][i][1]);
                sYh[row * 32 + cq * 2 + 1] = pack_bf2(acc[1][i][2], acc[1][i][3]);
            } else {
                *(float2*)&sXY[row * 52 + 48] = make_float2(acc[0][i][0], acc[0][i][1]);
                sYh[row * 32 + 24] = pack_bf2(acc[0 + 1][i][0], acc[1][i][1]);
            }
        }
    }
    if (tid < MT6 * 2) sXY[(tid >> 1) * 52 + 50 + (tid & 1)] = 0.f;      // fp32 pads
    for (int i = tid; i < MT6 * 7; i += 128)                              // bf16 pads 25..31
        sYh[(i / 7) * 32 + 25 + (i % 7)] = 0u;
    __syncthreads();

    // ---- flush Ya (fp32) + Ybh (bf16) + dots ----
    {
        float4* dst = (float4*)(Ya + (size_t)m0 * LD);
        for (int i = tid; i < nrow * 13; i += 128) dst[i] = ((const float4*)sXY)[i];
        float4* dsth = (float4*)(Ybh + (size_t)m0 * LDH);
        for (int i = tid; i < nrow * 8; i += 128) dsth[i] = ((const float4*)sYh)[i];
        if (tid < nrow) {
            const float* rowp = &sXY[tid * 52];
            float d = 0.f;
            for (int k = 0; k < DD; k++) d += rowp[k] * sa[k];
            shOut[m0 + tid] = d;
            const unsigned int* rh = &sYh[tid * 32];
            float d2 = 0.f;
            for (int p = 0; p < 25; p++) {
                unsigned int v = rh[p];
                d2 += __uint_as_float(v << 16) * sa[2 * p]
                    + __uint_as_float(v & 0xFFFF0000u) * sa[2 * p + 1];
            }
            stOut[m0 + tid] = d2;
        }
    }

    // ---- stage + flush acc[2] (Ed, fp32) ----
    if (NMAT == 3) {
        __syncthreads();
        if (active) {
            #pragma unroll
            for (int i = 0; i < 8; i++) {
                int row = r0 + i;
                if (cq < 12) {
                    *(float4*)&sXY[row * 52 + j0] =
                        make_float4(acc[2][i][0], acc[2][i][1], acc[2][i][2], acc[2][i][3]);
                } else {
                    *(float2*)&sXY[row * 52 + 48] = make_float2(acc[2][i][0], acc[2][i][1]);
                }
            }
        }
        // pad cols 50,51 still zero from previous phase writes
        if (tid < MT6 * 2) sXY[(tid >> 1) * 52 + 50 + (tid & 1)] = 0.f;
        __syncthreads();
        float4* dst = (float4*)(Yc + (size_t)m0 * LD);
        for (int i = tid; i < nrow * 13; i += 128) dst[i] = ((const float4*)sXY)[i];
    }
}

// rel_out = (relu?) Rin @ Wr (stride ld_rel); RW_out = Rin @ Wmid (fp32 stride LD2)
__global__ void rel_pre_kernel(const float* __restrict__ Rin, int ld_in,
                               const float* __restrict__ Wr,
                               const float* __restrict__ Wmid,
                               int do_relu,
                               float* __restrict__ rel_out, int ld_rel,
                               float* __restrict__ RW_out)
{
    __shared__ float sWr[DD * DD];
    __shared__ float sWm[DD * DD];
    for (int i = threadIdx.x; i < DD * DD; i += blockDim.x) {
        sWr[i] = Wr[i];
        sWm[i] = Wmid[i];
    }
    __syncthreads();
    int idx = blockIdx.x * blockDim.x + threadIdx.x;
    if (idx >= N_REL * DD) return;
    int m = idx / DD, j = idx - m * DD;
    const float* x = Rin + (size_t)m * ld_in;
    float ar = 0.f, am = 0.f;
    for (int k = 0; k < DD; k++) {
        float xv = x[k];
        ar += xv * sWr[k * DD + j];
        am += xv * sWm[k * DD + j];
    }
    if (do_relu) ar = fmaxf(ar, 0.f);
    rel_out[(size_t)m * ld_rel + j] = ar;
    RW_out[(size_t)m * LD2 + j] = am;
    if (j < LD2 - DD) RW_out[(size_t)m * LD2 + DD + j] = 0.f;
}

// sr[m] = RW[m][:50] . a
__global__ void sr_kernel(const float* __restrict__ RW,
                          const float* __restrict__ avec,
                          float* __restrict__ sr)
{
    int m = blockIdx.x * blockDim.x + threadIdx.x;
    if (m >= N_REL) return;
    float d = 0.f;
    for (int k = 0; k < DD; k++) d += RW[(size_t)m * LD2 + k] * avec[k];
    sr[m] = d;
}

// ---------------------------------------------------------------------------
// CSR build, two-level multisplit (line-dense writes)
// ---------------------------------------------------------------------------
__global__ void hist_kernel(const int* __restrict__ h, int* __restrict__ counts, int nE)
{
    int e = blockIdx.x * blockDim.x + threadIdx.x;
    if (e < nE) atomicAdd(&counts[h[e]], 1);
}

__global__ void coarse_kernel(const int* __restrict__ counts,
                              int* __restrict__ cbase,
                              int* __restrict__ ccur)
{
    __shared__ int s[256];
    const int b = threadIdx.x;
    int sum = 0;
    if (b < NB) {
        const int u0 = b << BBITS;
        const int nm = min(512, N_ENT - u0);
        const int4* c4 = (const int4*)(counts + u0);
        for (int k = 0; k < nm / 4; k++) {
            int4 v = c4[k];
            sum += v.x + v.y + v.z + v.w;
        }
    }
    s[b] = sum;
    __syncthreads();
    for (int off = 1; off < 256; off <<= 1) {
        int v = (b >= off) ? s[b - off] : 0;
        __syncthreads();
        s[b] += v;
        __syncthreads();
    }
    if (b < NB) {
        int excl = s[b] - sum;
        cbase[b] = excl;
        ccur[b] = excl;
    }
    if (b == NB - 1) cbase[NB] = s[b];
}

__global__ void assign2_kernel(const int* __restrict__ counts,
                               const int* __restrict__ cbase,
                               int* __restrict__ s0,
                               int* __restrict__ cursor)
{
    const int w = (blockIdx.x * blockDim.x + threadIdx.x) >> 6;
    if (w >= NB) return;
    const int lane = threadIdx.x & 63;
    const int u0 = (w << BBITS) + lane * 8;
    int pre[8];
    int s = 0;
    #pragma unroll
    for (int k = 0; k < 8; k++) {
        int u = u0 + k;
        int c = (u < N_ENT) ? counts[u] : 0;
        pre[k] = s;
        s += c;
    }
    int incl = s;
    #pragma unroll
    for (int off = 1; off < 64; off <<= 1) {
        int v = __shfl_up(incl, off);
        if (lane >= off) incl += v;
    }
    const int base = cbase[w] + incl - s;
    #pragma unroll
    for (int k = 0; k < 8; k++) {
        int u = u0 + k;
        if (u < N_ENT) {
            s0[u] = base + pre[k];
            cursor[u] = base + pre[k];
        }
    }
}

// S1: LDS multisplit into NB staged bucket regions. word = (e<<9)|(h&511)
__global__ __launch_bounds__(256) void bucket_scatter_kernel(
    const int* __restrict__ h,
    int* __restrict__ ccur,
    unsigned int* __restrict__ staged, int nE)
{
    __shared__ int sHist[NB];
    __shared__ int sScan[256];
    __shared__ int sBase[NB];
    __shared__ int sCur[NB];
    __shared__ int sGb[NB];
    __shared__ unsigned int sBuf[CHUNK];
    __shared__ unsigned char sBkt[CHUNK];

    const int tid = threadIdx.x;
    const int e0 = blockIdx.x * CHUNK;
    const int n = min(CHUNK, nE - e0);

    for (int i = tid; i < NB; i += 256) sHist[i] = 0;
    __syncthreads();

    #pragma unroll
    for (int k = 0; k < CHUNK / 256; k++) {
        int e = e0 + k * 256 + tid;
        if (e < nE) atomicAdd(&sHist[h[e] >> BBITS], 1);
    }
    __syncthreads();

    int v = (tid < NB) ? sHist[tid] : 0;
    sScan[tid] = v;
    __syncthreads();
    for (int off = 1; off < 256; off <<= 1) {
        int x = (tid >= off) ? sScan[tid - off] : 0;
        __syncthreads();
        sScan[tid] += x;
        __syncthreads();
    }
    if (tid < NB) {
        int excl = sScan[tid] - v;
        sBase[tid] = excl;
        sCur[tid] = excl;
    }
    __syncthreads();

    #pragma unroll
    for (int k = 0; k < CHUNK / 256; k++) {
        int e = e0 + k * 256 + tid;
        if (e < nE) {
            int hv = h[e];
            int b = hv >> BBITS;
            int pos = atomicAdd(&sCur[b], 1);
            sBuf[pos] = ((unsigned int)e << BBITS) | (unsigned int)(hv & BMASK);
            sBkt[pos] = (unsigned char)b;
        }
    }
    __syncthreads();

    if (tid < NB) {
        int cnt = sHist[tid];
        sGb[tid] = cnt ? atomicAdd(&ccur[tid], cnt) : 0;
    }
    __syncthreads();

    for (int i = tid; i < n; i += 256) {
        int b = sBkt[i];
        staged[sGb[b] + (i - sBase[b])] = sBuf[i];
    }
}

// S2: one block per bucket; exact placement into contiguous rtp window
__global__ void final_scatter_kernel(const unsigned int* __restrict__ staged,
                                     const int* __restrict__ cbase,
                                     const int* __restrict__ r,
                                     const int* __restrict__ t,
                                     int* __restrict__ cursor,
                                     unsigned int* __restrict__ rtp)
{
    const int b = blockIdx.x;
    const int i0 = cbase[b], i1 = cbase[b + 1];
    for (int i = i0 + threadIdx.x; i < i1; i += 256) {
        unsigned int w = staged[i];
        int e = w >> BBITS;
        int u = (b << BBITS) | (int)(w & BMASK);
        int pos = atomicAdd(&cursor[u], 1);
        rtp[pos] = ((unsigned int)r[e] << T_BITS) | (unsigned int)t[e];
    }
}

// ---------------------------------------------------------------------------
// Fused score + accumulate, one WAVE per head. EW3 gathered as bf16 (1 line).
// ---------------------------------------------------------------------------
__global__ __launch_bounds__(256) void accum_fused_kernel(
    const int* __restrict__ s0v,
    const int* __restrict__ counts,
    const unsigned int* __restrict__ rtp,
    const float* __restrict__ sh,
    const float* __restrict__ sr,
    const float* __restrict__ st,
    const float* __restrict__ EW1,
    const float* __restrict__ RW,
    const unsigned short* __restrict__ EW3h,
    const float* __restrict__ base,
    float* __restrict__ outp, int full_ld)
{
    const int u = (blockIdx.x * blockDim.x + threadIdx.x) >> 6;  // wave id
    if (u >= N_ENT) return;
    const int lane = threadIdx.x & 63;
    const int eg = lane / 13;          // 0..4 (eg==4 -> lanes 52..63 idle)
    const int q  = lane - eg * 13;

    const int b = s0v[u];
    const int c = counts[u];
    const float shu = sh[u];

    float4 acc = make_float4(0.f, 0.f, 0.f, 0.f);
    float asum = 0.f;

    if (eg < 4) {
        for (int i = eg; i < c; i += 4) {
            unsigned int w = rtp[b + i];
            int rr = w >> T_BITS;
            int tt = w & T_MASK;
            float sc = shu + sr[rr] + st[tt];
            sc = sc >= 0.f ? sc : 0.2f * sc;
            float ex = __expf(sc);
            float4 vr = *(const float4*)(RW + (size_t)rr * LD2 + 4 * q);
            uint2 th = *(const uint2*)(EW3h + (size_t)tt * LDH + 4 * q);
            float t0 = __uint_as_float(th.x << 16);
            float t1 = __uint_as_float(th.x & 0xFFFF0000u);
            float t2 = __uint_as_float(th.y << 16);
            float t3 = __uint_as_float(th.y & 0xFFFF0000u);
            asum += ex;
            acc.x += ex * (vr.x + t0);
            acc.y += ex * (vr.y + t1);
            acc.z += ex * (vr.z + t2);
            acc.w += ex * (vr.w + t3);
        }
    }

    acc.x += __shfl_down(acc.x, 26); acc.y += __shfl_down(acc.y, 26);
    acc.z += __shfl_down(acc.z, 26); acc.w += __shfl_down(acc.w, 26);
    asum  += __shfl_down(asum, 26);
    acc.x += __shfl_down(acc.x, 13); acc.y += __shfl_down(acc.y, 13);
    acc.z += __shfl_down(acc.z, 13); acc.w += __shfl_down(acc.w, 13);
    asum  += __shfl_down(asum, 13);

    if (lane >= 13) return;

    if (asum > 0.f) {
        float inv = 1.f / asum;
        float4 w1 = *(const float4*)(EW1 + (size_t)u * LD + 4 * lane);
        acc.x = w1.x + acc.x * inv;
        acc.y = w1.y + acc.y * inv;
        acc.z = w1.z + acc.z * inv;
        acc.w = w1.w + acc.w * inv;
    }
    if (base) {
        float4 bb = *(const float4*)(base + (size_t)u * LD + 4 * lane);
        acc.x += bb.x; acc.y += bb.y; acc.z += bb.z; acc.w += bb.w;
    }
    if (full_ld) {
        *(float4*)(outp + (size_t)u * LD + 4 * lane) = acc;
    } else {
        int j0 = 4 * lane;
        float v[4] = { acc.x, acc.y, acc.z, acc.w };
        #pragma unroll
        for (int cc = 0; cc < 4; cc++)
            if (j0 + cc < DD) outp[(size_t)u * DD + j0 + cc] = v[cc];
    }
}

// ---------------------------------------------------------------------------
extern "C" void kernel_launch(void* const* d_in, const int* in_sizes, int n_in,
                              void* d_out, int out_size, void* d_ws, size_t ws_size,
                              hipStream_t stream)
{
    const int*   h   = (const int*)d_in[0];
    const int*   r   = (const int*)d_in[1];
    const int*   t   = (const int*)d_in[2];
    const float* E   = (const float*)d_in[3];
    const float* R   = (const float*)d_in[4];
    const float* W0  = (const float*)d_in[5];
    const float* a0  = (const float*)d_in[6];
    const float* Wr0 = (const float*)d_in[7];
    const float* W1  = (const float*)d_in[8];
    const float* a1  = (const float*)d_in[9];
    const float* Wr1 = (const float*)d_in[10];
    const float* Wd  = (const float*)d_in[11];
    const float* bd  = (const float*)d_in[12];

    float* out_ent = (float*)d_out;                 // [N_ENT, DD] stride DD
    float* out_rel = out_ent + (size_t)N_ENT * DD;  // [N_REL, DD] stride DD

    // workspace layout (~94 MB)
    float* ws_f  = (float*)d_ws;
    float* EW1   = ws_f;                                   // N_ENT*LD
    float* Ed    = EW1  + (size_t)N_ENT * LD;              // N_ENT*LD
    float* e0    = Ed   + (size_t)N_ENT * LD;              // N_ENT*LD
    unsigned short* EW3h = (unsigned short*)(e0 + (size_t)N_ENT * LD);  // N_ENT*LDH bf16
    float* RW    = (float*)(EW3h + (size_t)N_ENT * LDH);   // N_REL*LD2
    float* rel0  = RW   + (size_t)N_REL * LD2;             // N_REL*LD
    float* sh    = rel0 + (size_t)N_REL * LD;              // N_ENT
    float* st    = sh   + N_ENT;                           // N_ENT
    float* sr    = st   + N_ENT;                           // N_REL
    int* counts  = (int*)(sr + N_REL);                     // N_ENT
    int* s0      = counts + N_ENT;                         // N_ENT
    int* cursor  = s0 + N_ENT;                             // N_ENT
    int* cbase   = cursor + N_ENT;                         // NB+1
    int* ccur    = cbase + NB + 1;                         // NB
    unsigned int* rtp    = (unsigned int*)(ccur + NB);     // N_EDGES
    unsigned int* staged = rtp + N_EDGES;                  // N_EDGES

    const int BLK = 256;
    const int gE   = (N_EDGES + BLK - 1) / BLK;
    const int gW   = (N_ENT + 3) / 4;            // accum: 1 wave/head
    const int gRD  = (N_REL * DD + BLK - 1) / BLK;
    const int gPRE = (N_ENT + MT6 - 1) / MT6;    // 1563
    const int gS1  = (N_EDGES + CHUNK - 1) / CHUNK;
    const int gA2  = (NB + 3) / 4;

    // ---- CSR build (two-level multisplit; shared by both layers) ----
    hipMemsetAsync(counts, 0, (size_t)N_ENT * sizeof(int), stream);
    hist_kernel<<<gE, BLK, 0, stream>>>(h, counts, N_EDGES);
    coarse_kernel<<<1, 256, 0, stream>>>(counts, cbase, ccur);
    assign2_kernel<<<gA2, BLK, 0, stream>>>(counts, cbase, s0, cursor);
    bucket_scatter_kernel<<<gS1, BLK, 0, stream>>>(h, ccur, staged, N_EDGES);
    final_scatter_kernel<<<NB, BLK, 0, stream>>>(staged, cbase, r, t, cursor, rtp);

    // ---- layer 0 precompute ----
    rel_pre_kernel<<<gRD, BLK, 0, stream>>>(R, DD, Wr0, W0 + DD * DD, 1,
                                            rel0, LD, RW);
    sr_kernel<<<2, BLK, 0, stream>>>(RW, a0, sr);
    ent_pre_v6<3><<<gPRE, 128, 0, stream>>>(E, DD, N_ENT, W0, W0 + 2 * DD * DD, Wd,
                                            bd, a0, EW1, EW3h, Ed, sh, st);

    // ---- layer 0 attention (fused score+softmax+accumulate) ----
    accum_fused_kernel<<<gW, BLK, 0, stream>>>(s0, counts, rtp, sh, sr, st,
                                               EW1, RW, EW3h, nullptr, e0, 1);

    // ---- layer 1 precompute ----
    rel_pre_kernel<<<gRD, BLK, 0, stream>>>(rel0, LD, Wr1, W1 + DD * DD, 0,
                                            out_rel, DD, RW);
    sr_kernel<<<2, BLK, 0, stream>>>(RW, a1, sr);
    ent_pre_v6<2><<<gPRE, 128, 0, stream>>>(e0, LD, N_ENT, W1, W1 + 2 * DD * DD,
                                            nullptr, nullptr, a1,
                                            EW1, EW3h, nullptr, sh, st);

    // ---- layer 1 attention + fused residual ----
    accum_fused_kernel<<<gW, BLK, 0, stream>>>(s0, counts, rtp, sh, sr, st,
                                               EW1, RW, EW3h, Ed, out_ent, 0);
}

// Round 11
// 556.215 us; speedup vs baseline: 1.1366x; 1.1366x over previous
//
#include <hip/hip_runtime.h>

#define N_ENT   100000
#define N_REL   500
#define DD      50
#define LD      52      // fp32 stride for sequentially-read tables (EW1/Ed/e0): 208 B
#define LD2     64      // fp32 stride for RW (L2-resident gather): 256 B
#define LDH     64      // bf16 stride for EW3h: 64 shorts = 128 B = 1 cache line
#define N_EDGES 2000000
#define T_BITS  17
#define T_MASK  0x1FFFF
#define BBITS   9                    // 512 entities per coarse bucket
#define BMASK   511
#define NB      196                  // ceil(N_ENT / 512)
#define CHUNK   8192                 // edges per bucket_scatter block

__device__ inline unsigned int pack_bf2(float x, float y) {
    unsigned int xu = __float_as_uint(x);
    unsigned int yu = __float_as_uint(y);
    xu = (xu + 0x7FFFu + ((xu >> 16) & 1u)) >> 16;   // round-to-nearest-even
    yu = (yu + 0x7FFFu + ((yu >> 16) & 1u)) >> 16;
    return xu | (yu << 16);
}
__device__ inline float bf_lo(unsigned int v) { return __uint_as_float(v << 16); }
__device__ inline float bf_hi(unsigned int v) { return __uint_as_float(v & 0xFFFF0000u); }

// ---------------------------------------------------------------------------
// ent_pre_v5 (R9 config — best measured): 2x2 tiles, MT=20, LDS staging at
// stride 52 (bank-spread), bf16 output for the gathered table.
//   Ya[m][:]  = X@Wa   fp32 stride LD  ; shOut[m] = row.a
//   Ybh[m][:] = X@Wb   bf16 stride LDH ; stOut[m] = row.a (dot from fp32)
//   Yc[m][:]  = X@Wc+bd fp32 stride LD   [NMAT==3 only]
// ---------------------------------------------------------------------------
template<int NMAT>
__global__ __launch_bounds__(256) void ent_pre_v5(
    const float* __restrict__ X, int ldX,
    const float* __restrict__ Wa,
    const float* __restrict__ Wb,
    const float* __restrict__ Wc,
    const float* __restrict__ bd,
    const float* __restrict__ avec,
    float* __restrict__ Ya,
    unsigned short* __restrict__ Ybh,
    float* __restrict__ Yc,
    float* __restrict__ shOut,
    float* __restrict__ stOut)
{
    constexpr int MT = 20;       // rows per block; N_ENT % MT == 0
    __shared__ __align__(16) float sW[NMAT][DD * DD];
    __shared__ __align__(16) float sX[MT * 52];   // reused as bf16 staging later
    __shared__ __align__(16) float sY[MT * 52];
    __shared__ float sa[DD];

    const int tid = threadIdx.x;

    for (int i = tid; i < DD * DD / 4; i += 256) {
        ((float4*)sW[0])[i] = ((const float4*)Wa)[i];
        ((float4*)sW[1])[i] = ((const float4*)Wb)[i];
        if (NMAT == 3) ((float4*)sW[2])[i] = ((const float4*)Wc)[i];
    }
    if (tid < DD) sa[tid] = avec[tid];

    const int m0 = blockIdx.x * MT;
    const int nX4 = MT * ldX / 4;
    const float4* xsrc = (const float4*)(X + (size_t)m0 * ldX);
    for (int i = tid; i < nX4; i += 256) ((float4*)sX)[i] = xsrc[i];
    __syncthreads();

    const bool active = (tid < 250);
    const int mp = active ? tid / 25 : 0;
    const int jp = active ? tid % 25 : 0;
    const int r0 = 2 * mp, r1 = 2 * mp + 1, j0 = 2 * jp;

    float acc[NMAT][2][2];
    #pragma unroll
    for (int t = 0; t < NMAT; t++)
        #pragma unroll
        for (int i = 0; i < 2; i++)
            #pragma unroll
            for (int c = 0; c < 2; c++) acc[t][i][c] = 0.f;

    if (active) {
        if (NMAT == 3) {
            float b0 = bd[j0], b1 = bd[j0 + 1];
            acc[2][0][0] = b0; acc[2][0][1] = b1;
            acc[2][1][0] = b0; acc[2][1][1] = b1;
        }
        const float* xr0 = &sX[r0 * ldX];
        const float* xr1 = &sX[r1 * ldX];
        for (int k = 0; k < DD; k++) {
            float x0 = xr0[k], x1 = xr1[k];
            #pragma unroll
            for (int t = 0; t < NMAT; t++) {
                float2 w = *(const float2*)&sW[t][k * DD + j0];
                acc[t][0][0] += x0 * w.x; acc[t][0][1] += x0 * w.y;
                acc[t][1][0] += x1 * w.x; acc[t][1][1] += x1 * w.y;
            }
        }
    }

    // zero fp32 pad cols 50,51
    if (tid < MT * 2) sY[(tid >> 1) * 52 + 50 + (tid & 1)] = 0.f;

    // ---- stage 0: Ya (fp32, stride LD) + sh dot ----
    if (active) {
        sY[r0 * 52 + j0]     = acc[0][0][0];
        sY[r0 * 52 + j0 + 1] = acc[0][0][1];
        sY[r1 * 52 + j0]     = acc[0][1][0];
        sY[r1 * 52 + j0 + 1] = acc[0][1][1];
    }
    __syncthreads();
    {
        float4* dst = (float4*)(Ya + (size_t)m0 * LD);
        for (int i = tid; i < MT * LD / 4; i += 256) dst[i] = ((const float4*)sY)[i];
        if (tid < MT) {
            const float* row = &sY[tid * 52];
            float d = 0.f;
            for (int k = 0; k < DD; k++) d += row[k] * sa[k];
            shOut[m0 + tid] = d;
        }
    }
    __syncthreads();

    // ---- stage 1: Ybh (bf16, stride LDH) + st dot (from fp32) ----
    unsigned int* sYhU = (unsigned int*)sX;       // sX dead after compute
    if (active) {
        sY[r0 * 52 + j0]     = acc[1][0][0];
        sY[r0 * 52 + j0 + 1] = acc[1][0][1];
        sY[r1 * 52 + j0]     = acc[1][1][0];
        sY[r1 * 52 + j0 + 1] = acc[1][1][1];
        sYhU[r0 * 32 + jp] = pack_bf2(acc[1][0][0], acc[1][0][1]);
        sYhU[r1 * 32 + jp] = pack_bf2(acc[1][1][0], acc[1][1][1]);
    }
    if (tid < MT * 7) sYhU[(tid / 7) * 32 + 25 + (tid % 7)] = 0u;  // bf16 pads
    __syncthreads();
    {
        float4* dst = (float4*)(Ybh + (size_t)m0 * LDH);
        for (int i = tid; i < MT * LDH * 2 / 16; i += 256) dst[i] = ((const float4*)sYhU)[i];
        if (tid < MT) {
            const float* row = &sY[tid * 52];
            float d = 0.f;
            for (int k = 0; k < DD; k++) d += row[k] * sa[k];
            stOut[m0 + tid] = d;
        }
    }

    // ---- stage 2: Yc (fp32, stride LD)  [NMAT==3] ----
    if (NMAT == 3) {
        __syncthreads();
        if (active) {
            sY[r0 * 52 + j0]     = acc[2][0][0];
            sY[r0 * 52 + j0 + 1] = acc[2][0][1];
            sY[r1 * 52 + j0]     = acc[2][1][0];
            sY[r1 * 52 + j0 + 1] = acc[2][1][1];
        }
        __syncthreads();
        float4* dst = (float4*)(Yc + (size_t)m0 * LD);
        for (int i = tid; i < MT * LD / 4; i += 256) dst[i] = ((const float4*)sY)[i];
    }
}

// rel_out = (relu?) Rin @ Wr (stride ld_rel); RW_out = Rin @ Wmid (fp32 stride LD2)
__global__ void rel_pre_kernel(const float* __restrict__ Rin, int ld_in,
                               const float* __restrict__ Wr,
                               const float* __restrict__ Wmid,
                               int do_relu,
                               float* __restrict__ rel_out, int ld_rel,
                               float* __restrict__ RW_out)
{
    __shared__ float sWr[DD * DD];
    __shared__ float sWm[DD * DD];
    for (int i = threadIdx.x; i < DD * DD; i += blockDim.x) {
        sWr[i] = Wr[i];
        sWm[i] = Wmid[i];
    }
    __syncthreads();
    int idx = blockIdx.x * blockDim.x + threadIdx.x;
    if (idx >= N_REL * DD) return;
    int m = idx / DD, j = idx - m * DD;
    const float* x = Rin + (size_t)m * ld_in;
    float ar = 0.f, am = 0.f;
    for (int k = 0; k < DD; k++) {
        float xv = x[k];
        ar += xv * sWr[k * DD + j];
        am += xv * sWm[k * DD + j];
    }
    if (do_relu) ar = fmaxf(ar, 0.f);
    rel_out[(size_t)m * ld_rel + j] = ar;
    RW_out[(size_t)m * LD2 + j] = am;
    if (j < LD2 - DD) RW_out[(size_t)m * LD2 + DD + j] = 0.f;
}

// sr[m] = RW[m][:50] . a
__global__ void sr_kernel(const float* __restrict__ RW,
                          const float* __restrict__ avec,
                          float* __restrict__ sr)
{
    int m = blockIdx.x * blockDim.x + threadIdx.x;
    if (m >= N_REL) return;
    float d = 0.f;
    for (int k = 0; k < DD; k++) d += RW[(size_t)m * LD2 + k] * avec[k];
    sr[m] = d;
}

// ---------------------------------------------------------------------------
// CSR build, two-level multisplit (line-dense writes)
// ---------------------------------------------------------------------------
__global__ void hist_kernel(const int* __restrict__ h, int* __restrict__ counts, int nE)
{
    int e = blockIdx.x * blockDim.x + threadIdx.x;
    if (e < nE) atomicAdd(&counts[h[e]], 1);
}

__global__ void coarse_kernel(const int* __restrict__ counts,
                              int* __restrict__ cbase,
                              int* __restrict__ ccur)
{
    __shared__ int s[256];
    const int b = threadIdx.x;
    int sum = 0;
    if (b < NB) {
        const int u0 = b << BBITS;
        const int nm = min(512, N_ENT - u0);
        const int4* c4 = (const int4*)(counts + u0);
        for (int k = 0; k < nm / 4; k++) {
            int4 v = c4[k];
            sum += v.x + v.y + v.z + v.w;
        }
    }
    s[b] = sum;
    __syncthreads();
    for (int off = 1; off < 256; off <<= 1) {
        int v = (b >= off) ? s[b - off] : 0;
        __syncthreads();
        s[b] += v;
        __syncthreads();
    }
    if (b < NB) {
        int excl = s[b] - sum;
        cbase[b] = excl;
        ccur[b] = excl;
    }
    if (b == NB - 1) cbase[NB] = s[b];
}

__global__ void assign2_kernel(const int* __restrict__ counts,
                               const int* __restrict__ cbase,
                               int* __restrict__ s0,
                               int* __restrict__ cursor)
{
    const int w = (blockIdx.x * blockDim.x + threadIdx.x) >> 6;
    if (w >= NB) return;
    const int lane = threadIdx.x & 63;
    const int u0 = (w << BBITS) + lane * 8;
    int pre[8];
    int s = 0;
    #pragma unroll
    for (int k = 0; k < 8; k++) {
        int u = u0 + k;
        int c = (u < N_ENT) ? counts[u] : 0;
        pre[k] = s;
        s += c;
    }
    int incl = s;
    #pragma unroll
    for (int off = 1; off < 64; off <<= 1) {
        int v = __shfl_up(incl, off);
        if (lane >= off) incl += v;
    }
    const int base = cbase[w] + incl - s;
    #pragma unroll
    for (int k = 0; k < 8; k++) {
        int u = u0 + k;
        if (u < N_ENT) {
            s0[u] = base + pre[k];
            cursor[u] = base + pre[k];
        }
    }
}

// S1: LDS multisplit into NB staged bucket regions. word = (e<<9)|(h&511)
__global__ __launch_bounds__(256) void bucket_scatter_kernel(
    const int* __restrict__ h,
    int* __restrict__ ccur,
    unsigned int* __restrict__ staged, int nE)
{
    __shared__ int sHist[NB];
    __shared__ int sScan[256];
    __shared__ int sBase[NB];
    __shared__ int sCur[NB];
    __shared__ int sGb[NB];
    __shared__ unsigned int sBuf[CHUNK];
    __shared__ unsigned char sBkt[CHUNK];

    const int tid = threadIdx.x;
    const int e0 = blockIdx.x * CHUNK;
    const int n = min(CHUNK, nE - e0);

    for (int i = tid; i < NB; i += 256) sHist[i] = 0;
    __syncthreads();

    #pragma unroll
    for (int k = 0; k < CHUNK / 256; k++) {
        int e = e0 + k * 256 + tid;
        if (e < nE) atomicAdd(&sHist[h[e] >> BBITS], 1);
    }
    __syncthreads();

    int v = (tid < NB) ? sHist[tid] : 0;
    sScan[tid] = v;
    __syncthreads();
    for (int off = 1; off < 256; off <<= 1) {
        int x = (tid >= off) ? sScan[tid - off] : 0;
        __syncthreads();
        sScan[tid] += x;
        __syncthreads();
    }
    if (tid < NB) {
        int excl = sScan[tid] - v;
        sBase[tid] = excl;
        sCur[tid] = excl;
    }
    __syncthreads();

    #pragma unroll
    for (int k = 0; k < CHUNK / 256; k++) {
        int e = e0 + k * 256 + tid;
        if (e < nE) {
            int hv = h[e];
            int b = hv >> BBITS;
            int pos = atomicAdd(&sCur[b], 1);
            sBuf[pos] = ((unsigned int)e << BBITS) | (unsigned int)(hv & BMASK);
            sBkt[pos] = (unsigned char)b;
        }
    }
    __syncthreads();

    if (tid < NB) {
        int cnt = sHist[tid];
        sGb[tid] = cnt ? atomicAdd(&ccur[tid], cnt) : 0;
    }
    __syncthreads();

    for (int i = tid; i < n; i += 256) {
        int b = sBkt[i];
        staged[sGb[b] + (i - sBase[b])] = sBuf[i];
    }
}

// S2: one block per bucket; exact placement into contiguous rtp window
__global__ void final_scatter_kernel(const unsigned int* __restrict__ staged,
                                     const int* __restrict__ cbase,
                                     const int* __restrict__ r,
                                     const int* __restrict__ t,
                                     int* __restrict__ cursor,
                                     unsigned int* __restrict__ rtp)
{
    const int b = blockIdx.x;
    const int i0 = cbase[b], i1 = cbase[b + 1];
    for (int i = i0 + threadIdx.x; i < i1; i += 256) {
        unsigned int w = staged[i];
        int e = w >> BBITS;
        int u = (b << BBITS) | (int)(w & BMASK);
        int pos = atomicAdd(&cursor[u], 1);
        rtp[pos] = ((unsigned int)r[e] << T_BITS) | (unsigned int)t[e];
    }
}

// ---------------------------------------------------------------------------
// Fused score + accumulate, one WAVE per head, v2 lane geometry:
// lane = eg*8 + q; eg in 0..7 (edge group), q in 0..7 (8-col group).
// Per edge: 8 lanes read one full 128B EW3h line (uint4 each) + 256B RW row
// (2 float4). 8 edges in flight per wave, all 64 lanes active.
// Fold egs via shfl_down(32,16,8); lanes 0..7 write cols 8q..8q+7.
// Pads (cols 50+) are zero in all tables -> pad outputs are exactly 0.
// ---------------------------------------------------------------------------
__global__ __launch_bounds__(256) void accum_fused_kernel(
    const int* __restrict__ s0v,
    const int* __restrict__ counts,
    const unsigned int* __restrict__ rtp,
    const float* __restrict__ sh,
    const float* __restrict__ sr,
    const float* __restrict__ st,
    const float* __restrict__ EW1,
    const float* __restrict__ RW,
    const unsigned short* __restrict__ EW3h,
    const float* __restrict__ base,
    float* __restrict__ outp, int full_ld)
{
    const int u = (blockIdx.x * blockDim.x + threadIdx.x) >> 6;  // wave id
    if (u >= N_ENT) return;
    const int lane = threadIdx.x & 63;
    const int eg = lane >> 3;
    const int q  = lane & 7;

    const int b = s0v[u];
    const int c = counts[u];
    const float shu = sh[u];

    float acc[8];
    #pragma unroll
    for (int k = 0; k < 8; k++) acc[k] = 0.f;
    float asum = 0.f;

    for (int i = eg; i < c; i += 8) {
        unsigned int w = rtp[b + i];
        int rr = w >> T_BITS;
        int tt = w & T_MASK;
        float sc = shu + sr[rr] + st[tt];
        sc = sc >= 0.f ? sc : 0.2f * sc;
        float ex = __expf(sc);
        uint4 th = *(const uint4*)(EW3h + (size_t)tt * LDH + 8 * q);   // cols 8q..8q+7
        float4 vr0 = *(const float4*)(RW + (size_t)rr * LD2 + 8 * q);
        float4 vr1 = *(const float4*)(RW + (size_t)rr * LD2 + 8 * q + 4);
        asum += ex;
        acc[0] += ex * (vr0.x + bf_lo(th.x));
        acc[1] += ex * (vr0.y + bf_hi(th.x));
        acc[2] += ex * (vr0.z + bf_lo(th.y));
        acc[3] += ex * (vr0.w + bf_hi(th.y));
        acc[4] += ex * (vr1.x + bf_lo(th.z));
        acc[5] += ex * (vr1.y + bf_hi(th.z));
        acc[6] += ex * (vr1.z + bf_lo(th.w));
        acc[7] += ex * (vr1.w + bf_hi(th.w));
    }

    #pragma unroll
    for (int off = 32; off >= 8; off >>= 1) {
        #pragma unroll
        for (int k = 0; k < 8; k++) acc[k] += __shfl_down(acc[k], off);
        asum += __shfl_down(asum, off);
    }

    if (lane >= 8) return;             // lanes 0..7 hold cols 8*lane..8*lane+7
    const int j0 = 8 * lane;
    if (j0 >= LD) return;              // q==7 -> cols 56.. out of range

    if (asum > 0.f) {
        float inv = 1.f / asum;
        if (j0 < 48) {
            float4 w1a = *(const float4*)(EW1 + (size_t)u * LD + j0);
            float4 w1b = *(const float4*)(EW1 + (size_t)u * LD + j0 + 4);
            acc[0] = w1a.x + acc[0] * inv; acc[1] = w1a.y + acc[1] * inv;
            acc[2] = w1a.z + acc[2] * inv; acc[3] = w1a.w + acc[3] * inv;
            acc[4] = w1b.x + acc[4] * inv; acc[5] = w1b.y + acc[5] * inv;
            acc[6] = w1b.z + acc[6] * inv; acc[7] = w1b.w + acc[7] * inv;
        } else {  // j0 == 48: cols 48,49 real; 50,51 pads (zero everywhere)
            float4 w1a = *(const float4*)(EW1 + (size_t)u * LD + 48);
            acc[0] = w1a.x + acc[0] * inv; acc[1] = w1a.y + acc[1] * inv;
            acc[2] = w1a.z + acc[2] * inv; acc[3] = w1a.w + acc[3] * inv;
        }
    }  // else: empty segment -> 0, matching ref
    if (base) {
        if (j0 < 48) {
            float4 ba = *(const float4*)(base + (size_t)u * LD + j0);
            float4 bb = *(const float4*)(base + (size_t)u * LD + j0 + 4);
            acc[0] += ba.x; acc[1] += ba.y; acc[2] += ba.z; acc[3] += ba.w;
            acc[4] += bb.x; acc[5] += bb.y; acc[6] += bb.z; acc[7] += bb.w;
        } else {
            float4 ba = *(const float4*)(base + (size_t)u * LD + 48);
            acc[0] += ba.x; acc[1] += ba.y; acc[2] += ba.z; acc[3] += ba.w;
        }
    }
    if (full_ld) {                      // stride LD=52, 16B-aligned
        if (j0 < 48) {
            *(float4*)(outp + (size_t)u * LD + j0) =
                make_float4(acc[0], acc[1], acc[2], acc[3]);
            *(float4*)(outp + (size_t)u * LD + j0 + 4) =
                make_float4(acc[4], acc[5], acc[6], acc[7]);
        } else {                        // cols 48..51 (50,51 are exact zeros)
            *(float4*)(outp + (size_t)u * LD + 48) =
                make_float4(acc[0], acc[1], acc[2], acc[3]);
        }
    } else {                            // stride DD=50, rows only 8B-aligned
        float* row = outp + (size_t)u * DD;
        if (j0 < 48) {
            *(float2*)(row + j0)     = make_float2(acc[0], acc[1]);
            *(float2*)(row + j0 + 2) = make_float2(acc[2], acc[3]);
            *(float2*)(row + j0 + 4) = make_float2(acc[4], acc[5]);
            *(float2*)(row + j0 + 6) = make_float2(acc[6], acc[7]);
        } else {
            *(float2*)(row + 48) = make_float2(acc[0], acc[1]);
        }
    }
}

// ---------------------------------------------------------------------------
extern "C" void kernel_launch(void* const* d_in, const int* in_sizes, int n_in,
                              void* d_out, int out_size, void* d_ws, size_t ws_size,
                              hipStream_t stream)
{
    const int*   h   = (const int*)d_in[0];
    const int*   r   = (const int*)d_in[1];
    const int*   t   = (const int*)d_in[2];
    const float* E   = (const float*)d_in[3];
    const float* R   = (const float*)d_in[4];
    const float* W0  = (const float*)d_in[5];
    const float* a0  = (const float*)d_in[6];
    const float* Wr0 = (const float*)d_in[7];
    const float* W1  = (const float*)d_in[8];
    const float* a1  = (const float*)d_in[9];
    const float* Wr1 = (const float*)d_in[10];
    const float* Wd  = (const float*)d_in[11];
    const float* bd  = (const float*)d_in[12];

    float* out_ent = (float*)d_out;                 // [N_ENT, DD] stride DD
    float* out_rel = out_ent + (size_t)N_ENT * DD;  // [N_REL, DD] stride DD

    // workspace layout (~94 MB)
    float* ws_f  = (float*)d_ws;
    float* EW1   = ws_f;                                   // N_ENT*LD
    float* Ed    = EW1  + (size_t)N_ENT * LD;              // N_ENT*LD
    float* e0    = Ed   + (size_t)N_ENT * LD;              // N_ENT*LD
    unsigned short* EW3h = (unsigned short*)(e0 + (size_t)N_ENT * LD);  // N_ENT*LDH bf16
    float* RW    = (float*)(EW3h + (size_t)N_ENT * LDH);   // N_REL*LD2
    float* rel0  = RW   + (size_t)N_REL * LD2;             // N_REL*LD
    float* sh    = rel0 + (size_t)N_REL * LD;              // N_ENT
    float* st    = sh   + N_ENT;                           // N_ENT
    float* sr    = st   + N_ENT;                           // N_REL
    int* counts  = (int*)(sr + N_REL);                     // N_ENT
    int* s0      = counts + N_ENT;                         // N_ENT
    int* cursor  = s0 + N_ENT;                             // N_ENT
    int* cbase   = cursor + N_ENT;                         // NB+1
    int* ccur    = cbase + NB + 1;                         // NB
    unsigned int* rtp    = (unsigned int*)(ccur + NB);     // N_EDGES
    unsigned int* staged = rtp + N_EDGES;                  // N_EDGES

    const int BLK = 256;
    const int gE   = (N_EDGES + BLK - 1) / BLK;
    const int gW   = (N_ENT + 3) / 4;            // accum: 1 wave/head
    const int gRD  = (N_REL * DD + BLK - 1) / BLK;
    const int gPRE = N_ENT / 20;
    const int gS1  = (N_EDGES + CHUNK - 1) / CHUNK;
    const int gA2  = (NB + 3) / 4;

    // ---- CSR build (two-level multisplit; shared by both layers) ----
    hipMemsetAsync(counts, 0, (size_t)N_ENT * sizeof(int), stream);
    hist_kernel<<<gE, BLK, 0, stream>>>(h, counts, N_EDGES);
    coarse_kernel<<<1, 256, 0, stream>>>(counts, cbase, ccur);
    assign2_kernel<<<gA2, BLK, 0, stream>>>(counts, cbase, s0, cursor);
    bucket_scatter_kernel<<<gS1, BLK, 0, stream>>>(h, ccur, staged, N_EDGES);
    final_scatter_kernel<<<NB, BLK, 0, stream>>>(staged, cbase, r, t, cursor, rtp);

    // ---- layer 0 precompute ----
    rel_pre_kernel<<<gRD, BLK, 0, stream>>>(R, DD, Wr0, W0 + DD * DD, 1,
                                            rel0, LD, RW);
    sr_kernel<<<2, BLK, 0, stream>>>(RW, a0, sr);
    ent_pre_v5<3><<<gPRE, BLK, 0, stream>>>(E, DD, W0, W0 + 2 * DD * DD, Wd, bd, a0,
                                            EW1, EW3h, Ed, sh, st);

    // ---- layer 0 attention (fused score+softmax+accumulate) ----
    accum_fused_kernel<<<gW, BLK, 0, stream>>>(s0, counts, rtp, sh, sr, st,
                                               EW1, RW, EW3h, nullptr, e0, 1);

    // ---- layer 1 precompute ----
    rel_pre_kernel<<<gRD, BLK, 0, stream>>>(rel0, LD, Wr1, W1 + DD * DD, 0,
                                            out_rel, DD, RW);
    sr_kernel<<<2, BLK, 0, stream>>>(RW, a1, sr);
    ent_pre_v5<2><<<gPRE, BLK, 0, stream>>>(e0, LD, W1, W1 + 2 * DD * DD,
                                            nullptr, nullptr, a1,
                                            EW1, EW3h, nullptr, sh, st);

    // ---- layer 1 attention + fused residual ----
    accum_fused_kernel<<<gW, BLK, 0, stream>>>(s0, counts, rtp, sh, sr, st,
                                               EW1, RW, EW3h, Ed, out_ent, 0);
}